// Round 1
// baseline (246.569 us; speedup 1.0000x reference)
//
#include <hip/hip_runtime.h>
#include <hip/hip_bf16.h>
#include <cstdint>

// Problem constants (match reference)
#define B_SZ     256
#define D_DIM    2048
#define N_PROXY  16384
#define P_POS    4
#define K_SEL    54        // BG_KNN + P
#define TEMP_INV 20.0f     // 1/0.05

typedef __bf16 bf16_t;
typedef __bf16 bf16x4 __attribute__((ext_vector_type(4)));
typedef __bf16 bf16x8 __attribute__((ext_vector_type(8)));
typedef float  f32x4  __attribute__((ext_vector_type(4)));

// ---------------------------------------------------------------------------
// Kernel 0: F fp32 [256,2048] -> Fb bf16 in MFMA-A fragment-major layout.
// frag slot g = (mb*64 + kt)*64 + lane holds A[m=mb*16+(lane&15)]
// [k = kt*32 + (lane>>4)*8 + j], j=0..7.  Also zeroes the loss accumulator
// (replaces the separate hipMemsetAsync dispatch; stream order makes it safe).
// ---------------------------------------------------------------------------
__global__ __launch_bounds__(256)
void conv_feat(const float* __restrict__ F, bf16_t* __restrict__ Fb,
               float* __restrict__ out) {
    int g    = blockIdx.x * 256 + threadIdx.x;   // 0..65535
    if (g == 0) *out = 0.0f;
    int lane = g & 63;
    int kt   = (g >> 6) & 63;
    int mb   = g >> 12;                          // 0..15
    int frow = lane & 15;
    int quad = (lane >> 4) & 3;
    const float* src = F + (size_t)(mb * 16 + frow) * D_DIM + kt * 32 + quad * 8;
    float4 lo = *(const float4*)src;
    float4 hi = *(const float4*)(src + 4);
    bf16x8 o = { (bf16_t)lo.x, (bf16_t)lo.y, (bf16_t)lo.z, (bf16_t)lo.w,
                 (bf16_t)hi.x, (bf16_t)hi.y, (bf16_t)hi.z, (bf16_t)hi.w };
    *(bf16x8*)(Fb + (size_t)g * 8) = o;
}

// ---------------------------------------------------------------------------
// Kernel 1: Sb = bf16((F @ em.T)/TEMP).  BM=256, BN=64, BK=32, grid 256.
// v2 vs the 246-µs version: B is staged ONCE per block (not once per wave)
// into a double-buffered frag-major LDS tile (2 x 4 KB), cutting the L1/VMEM
// return traffic from 48 KB/step/CU to 24 KB/step/CU.  8 waves of 64 (512
// threads, ~100 VGPRs) give 2 waves/SIMD so waitcnt stalls cross-cover
// (the old kernel was ~280 VGPRs -> 1 wave/SIMD, every stall exposed).
// A stays register-direct from the L2-hot frag-major Fb.  All fragment and
// LDS layouts are identical to the verified kernel.
// ---------------------------------------------------------------------------
__global__ __launch_bounds__(512, 2)
void gemm_score(const bf16_t* __restrict__ Fb, const float* __restrict__ E,
                bf16_t* __restrict__ Sb) {
    const int tid  = threadIdx.x;
    const int bn   = blockIdx.x;          // 64-col n-stripe
    const int lane = tid & 63;
    const int w    = tid >> 6;            // wave 0..7, owns rows w*32..w*32+31
    const int frow = lane & 15;
    const int quad = (lane >> 4) & 3;

    // Shared double-buffered B tile in MFMA-B fragment-major layout:
    // frag n (512 bf16 = 1 KB) at n*512, lane-slot l' = fr+16*quad at l'*8.
    __shared__ bf16_t Bls[2][2048];       // 8 KB

    f32x4 acc[2][4] = {};                 // [m][n]

    // ---- B cooperative staging: 64 rows x 32 fp32 per K-step.
    // 512 threads x one float4 covers the slab exactly once.
    const int r  = tid >> 3;              // 0..63  (proxy row within stripe)
    const int c4 = (tid & 7) * 4;         // fp32 col within 32
    const float* bsrc = E + (size_t)(bn * 64 + r) * D_DIM + c4;
    const int bdst = (r >> 4) * 512 + ((r & 15) + 16 * (c4 >> 3)) * 8
                   + ((c4 >> 2) & 1) * 4;

    // A frag (m, kt) at Fb[((w*2+m)*64 + kt)*512 + lane*8]
    const bf16_t* Ab[2];
    Ab[0] = Fb + (size_t)((w * 2 + 0) * 64) * 512 + lane * 8;
    Ab[1] = Fb + (size_t)((w * 2 + 1) * 64) * 512 + lane * 8;

    float4 Brg[2];                        // B prefetch regs (compile-time idx)
    bf16x8 af[2][2];                      // A frags, 1 step ahead

    // ---- prologue: stage kt=0 ----
    Brg[0]   = *(const float4*)(bsrc);
    af[0][0] = *(const bf16x8*)(Ab[0]);
    af[0][1] = *(const bf16x8*)(Ab[1]);
    {
        bf16x4 h = { (bf16_t)Brg[0].x, (bf16_t)Brg[0].y,
                     (bf16_t)Brg[0].z, (bf16_t)Brg[0].w };
        *(bf16x4*)(&Bls[0][0] + bdst) = h;
    }
    __syncthreads();

    // All register-array indices below are literal constants (rule: runtime-
    // indexed ext_vector arrays go to scratch), KT appears only in addresses
    // and uniform branches.
#define GSTEP(CUR, KT)                                                         \
    {                                                                          \
        if ((KT) + 1 < 64) {                                                   \
            Brg[(CUR) ^ 1]   = *(const float4*)(bsrc + ((KT) + 1) * 32);       \
            af[(CUR) ^ 1][0] = *(const bf16x8*)(Ab[0] + ((KT) + 1) * 512);     \
            af[(CUR) ^ 1][1] = *(const bf16x8*)(Ab[1] + ((KT) + 1) * 512);     \
        }                                                                      \
        bf16x8 bg[4];                                                          \
        _Pragma("unroll")                                                      \
        for (int n = 0; n < 4; ++n)                                            \
            bg[n] = *(const bf16x8*)(&Bls[CUR][0] + n * 512 + lane * 8);       \
        _Pragma("unroll")                                                      \
        for (int m = 0; m < 2; ++m)                                            \
            _Pragma("unroll")                                                  \
            for (int n = 0; n < 4; ++n)                                        \
                acc[m][n] = __builtin_amdgcn_mfma_f32_16x16x32_bf16(           \
                    af[CUR][m], bg[n], acc[m][n], 0, 0, 0);                    \
        if ((KT) + 1 < 64) {                                                   \
            bf16x4 h = { (bf16_t)Brg[(CUR) ^ 1].x, (bf16_t)Brg[(CUR) ^ 1].y,   \
                         (bf16_t)Brg[(CUR) ^ 1].z, (bf16_t)Brg[(CUR) ^ 1].w }; \
            *(bf16x4*)(&Bls[(CUR) ^ 1][0] + bdst) = h;                         \
        }                                                                      \
        __syncthreads();                                                       \
    }

    for (int k0 = 0; k0 < 64; k0 += 2) {
        GSTEP(0, k0)
        GSTEP(1, k0 + 1)
    }
#undef GSTEP

    // ---- epilogue: C/D layout col=lane&15, row=quad*4+i; fold 1/TEMP ----
#pragma unroll
    for (int m = 0; m < 2; ++m) {
        int gr = w * 32 + m * 16 + quad * 4;
#pragma unroll
        for (int n = 0; n < 4; ++n) {
            int gc = bn * 64 + n * 16 + frow;
#pragma unroll
            for (int i = 0; i < 4; ++i)
                Sb[(size_t)(gr + i) * N_PROXY + gc] =
                    (bf16_t)(acc[m][n][i] * TEMP_INV);
        }
    }
}

// ---------------------------------------------------------------------------
// Kernel 2: per-row top-K + log-softmax loss on bf16 scores.
// 512 threads/row, 32 keys/thread; 16-bit radix select with early exit.
// (unchanged this round — one structural change at a time)
// ---------------------------------------------------------------------------
__device__ __forceinline__ float key16_to_float(uint32_t k) {
    uint32_t bits16 = (k & 0x8000u) ? (k ^ 0x8000u) : ((~k) & 0xFFFFu);
    return __uint_as_float(bits16 << 16);
}

__device__ __forceinline__ int block_sum_i(int v, int tid, volatile int* rbuf) {
#pragma unroll
    for (int o = 32; o > 0; o >>= 1) v += __shfl_down(v, o, 64);
    __syncthreads();
    if ((tid & 63) == 0) rbuf[tid >> 6] = v;
    __syncthreads();
    int s = 0;
#pragma unroll
    for (int w = 0; w < 8; ++w) s += rbuf[w];
    return s;
}

__device__ __forceinline__ float block_sum_f(float v, int tid, volatile float* rbuf) {
#pragma unroll
    for (int o = 32; o > 0; o >>= 1) v += __shfl_down(v, o, 64);
    __syncthreads();
    if ((tid & 63) == 0) rbuf[tid >> 6] = v;
    __syncthreads();
    float s = 0.0f;
#pragma unroll
    for (int w = 0; w < 8; ++w) s += rbuf[w];
    return s;
}

__device__ __forceinline__ uint32_t block_max_u(uint32_t v, int tid,
                                                volatile uint32_t* rbuf) {
#pragma unroll
    for (int o = 32; o > 0; o >>= 1) {
        uint32_t w = __shfl_down(v, o, 64);
        v = (w > v) ? w : v;
    }
    __syncthreads();
    if ((tid & 63) == 0) rbuf[tid >> 6] = v;
    __syncthreads();
    uint32_t r = 0;
#pragma unroll
    for (int w = 0; w < 8; ++w) r = rbuf[w] > r ? rbuf[w] : r;
    return r;
}

__global__ __launch_bounds__(512)
void topk_loss(const bf16_t* __restrict__ S, const int* __restrict__ targets,
               const int* __restrict__ plabel, const int* __restrict__ ptable,
               float* __restrict__ out) {
    const int b    = blockIdx.x;
    const int tid  = threadIdx.x;
    const int lane = tid & 63;
    const int wave = tid >> 6;

    __shared__ int      sh_pos[4];
    __shared__ float    sh_pv[4];
    __shared__ int      sh_d;
    __shared__ int      rbuf_i[8];
    __shared__ float    rbuf_f[8];
    __shared__ uint32_t rbuf_u[8];
    __shared__ uint32_t cand_ls[64];
    __shared__ int      candcnt;
    __shared__ float    sh_numbg;

    const bf16_t* row = S + (size_t)b * N_PROXY;

    if (tid == 0) {
        int t  = targets[b];
        int py = plabel[t];
        int pos[4]; int d = 0;
        for (int j = 0; j < 4; ++j) {
            int p = ptable[py * 4 + j];
            bool dup = false;
            for (int i = 0; i < d; ++i) dup = dup || (pos[i] == p);
            if (!dup) pos[d++] = p;
        }
        sh_d = d;
        for (int j = 0; j < 4; ++j) sh_pos[j] = (j < d) ? pos[j] : -1;
        for (int j = 0; j < 4; ++j) sh_pv[j]  = (j < d) ? (float)row[pos[j]] : 0.0f;
        candcnt = 0;
    }
    __syncthreads();

    const int d  = sh_d;
    const int p0 = sh_pos[0], p1 = sh_pos[1], p2 = sh_pos[2], p3 = sh_pos[3];
    float pv[4];
#pragma unroll
    for (int j = 0; j < 4; ++j) pv[j] = sh_pv[j];

    // ---- 32 bf16 logits/thread as 16-bit sortable keys; positives -> 0 ----
    uint32_t keys[32];
#pragma unroll
    for (int j = 0; j < 4; ++j) {
        int g8 = j * 512 + tid;                     // 8-element granule
        ushort v[8];
        *(uint4*)v = *(const uint4*)(row + (size_t)g8 * 8);
#pragma unroll
        for (int q = 0; q < 8; ++q) {
            int idx = g8 * 8 + q;
            bool isp = (idx == p0) | (idx == p1) | (idx == p2) | (idx == p3);
            uint32_t bits = v[q];
            uint32_t key  = (bits & 0x8000u) ? ((~bits) & 0xFFFFu)
                                             : (bits | 0x8000u);
            keys[j * 8 + q] = isp ? 0u : key;
        }
    }

    const int need = K_SEL - d;              // backgrounds in the top-54 set

    // ---- 16-bit radix select with early exit ----
    uint32_t T = 0;
    for (int bit = 15; bit >= 0; --bit) {
        uint32_t cnd = T | (1u << bit);
        int c = 0;
#pragma unroll
        for (int j = 0; j < 32; ++j) c += (keys[j] >= cnd) ? 1 : 0;
        int ct = block_sum_i(c, tid, rbuf_i);
        if (ct >= need) {
            T = cnd;
            if (ct == need) break;           // selected set is exactly top-need
        }
    }
    const float vT = key16_to_float(T);

    // ---- stability max over backgrounds + positives ----
    uint32_t kmax = 0;
#pragma unroll
    for (int j = 0; j < 32; ++j) kmax = keys[j] > kmax ? keys[j] : kmax;
    kmax = block_max_u(kmax, tid, rbuf_u);
    float mx = key16_to_float(kmax);
    for (int j = 0; j < 4; ++j) if (j < d && pv[j] > mx) mx = pv[j];

    // ---- lse over selected set: strict-greater + exact tie fill + pos ----
    int c1 = 0; float se = 0.0f;
#pragma unroll
    for (int j = 0; j < 32; ++j) {
        if (keys[j] > T) { c1 += 1; se += __expf(key16_to_float(keys[j]) - mx); }
    }
    int   c1t = block_sum_i(c1, tid, rbuf_i);
    float set = block_sum_f(se, tid, rbuf_f);
    set += (float)(need - c1t) * __expf(vT - mx);
    for (int j = 0; j < 4; ++j) if (j < d) set += __expf(pv[j] - mx);
    const float lse = mx + logf(set);

    // ---- numerator: distinct positives + top (P-d) background values ----
    float num = 0.0f;
    for (int j = 0; j < 4; ++j) if (j < d) num += pv[j];
    if (d < P_POS) {
#pragma unroll
        for (int j = 0; j < 32; ++j) {
            if (keys[j] > T) {
                int p = atomicAdd(&candcnt, 1);
                cand_ls[p] = keys[j];
            }
        }
        __syncthreads();
        if (wave == 0) {
            const int cc = candcnt;
            uint32_t v = (lane < cc) ? cand_ls[lane] : T;   // pad with T (exact)
            float s = 0.0f;
            const int need2 = P_POS - d;                    // 1..3
            for (int it = 0; it < need2; ++it) {
                uint32_t m = v;
#pragma unroll
                for (int o = 32; o > 0; o >>= 1) {
                    uint32_t w = __shfl_xor(m, o, 64);
                    m = (w > m) ? w : m;
                }
                s += key16_to_float(m);
                unsigned long long msk = __ballot(v == m);
                int first = __ffsll(msk) - 1;
                if (lane == first) v = 0u;
            }
            if (lane == 0) sh_numbg = s;
        }
        __syncthreads();
        num += sh_numbg;
    }

    const float loss_b = lse - num * (1.0f / P_POS);
    if (tid == 0) atomicAdd(out, loss_b * (1.0f / B_SZ));
}

// ---------------------------------------------------------------------------
extern "C" void kernel_launch(void* const* d_in, const int* in_sizes, int n_in,
                              void* d_out, int out_size, void* d_ws, size_t ws_size,
                              hipStream_t stream) {
    const float* F       = (const float*)d_in[0];   // features [256,2048]
    const float* E       = (const float*)d_in[1];   // global_memory [16384,2048]
    const int*   targets = (const int*)d_in[2];     // [256]
    const int*   plabel  = (const int*)d_in[3];     // [32768]
    const int*   ptable  = (const int*)d_in[4];     // [4096,4]

    bf16_t* Fb = (bf16_t*)d_ws;                                     // 1 MB, frag-major
    bf16_t* Sb = (bf16_t*)((char*)d_ws + (size_t)B_SZ * D_DIM * 2); // 8 MB
    float*  out = (float*)d_out;

    // out is zeroed by conv_feat (stream-ordered before topk_loss's atomics);
    // the separate hipMemsetAsync dispatch is gone.
    hipLaunchKernelGGL(conv_feat, dim3(256), dim3(256), 0, stream, F, Fb, out);
    hipLaunchKernelGGL(gemm_score, dim3(N_PROXY / 64), dim3(512), 0, stream,
                       Fb, E, Sb);
    hipLaunchKernelGGL(topk_loss, dim3(B_SZ), dim3(512), 0, stream,
                       Sb, targets, plabel, ptable, out);
}

// Round 2
// 239.141 us; speedup vs baseline: 1.0311x; 1.0311x over previous
//
#include <hip/hip_runtime.h>
#include <hip/hip_bf16.h>
#include <cstdint>

// Problem constants (match reference)
#define B_SZ     256
#define D_DIM    2048
#define N_PROXY  16384
#define P_POS    4
#define K_SEL    54        // BG_KNN + P
#define TEMP_INV 20.0f     // 1/0.05

typedef __bf16 bf16_t;
typedef __bf16 bf16x4 __attribute__((ext_vector_type(4)));
typedef __bf16 bf16x8 __attribute__((ext_vector_type(8)));
typedef float  f32x4  __attribute__((ext_vector_type(4)));

// ---------------------------------------------------------------------------
// Kernel 0: F fp32 [256,2048] -> Fb bf16 in MFMA-A fragment-major layout.
// frag slot g = (mb*64 + kt)*64 + lane holds A[m=mb*16+(lane&15)]
// [k = kt*32 + (lane>>4)*8 + j], j=0..7.  Also zeroes the loss accumulator.
// ---------------------------------------------------------------------------
__global__ __launch_bounds__(256)
void conv_feat(const float* __restrict__ F, bf16_t* __restrict__ Fb,
               float* __restrict__ out) {
    int g    = blockIdx.x * 256 + threadIdx.x;   // 0..65535
    if (g == 0) *out = 0.0f;
    int lane = g & 63;
    int kt   = (g >> 6) & 63;
    int mb   = g >> 12;                          // 0..15
    int frow = lane & 15;
    int quad = (lane >> 4) & 3;
    const float* src = F + (size_t)(mb * 16 + frow) * D_DIM + kt * 32 + quad * 8;
    float4 lo = *(const float4*)src;
    float4 hi = *(const float4*)(src + 4);
    bf16x8 o = { (bf16_t)lo.x, (bf16_t)lo.y, (bf16_t)lo.z, (bf16_t)lo.w,
                 (bf16_t)hi.x, (bf16_t)hi.y, (bf16_t)hi.z, (bf16_t)hi.w };
    *(bf16x8*)(Fb + (size_t)g * 8) = o;
}

// ---------------------------------------------------------------------------
// Kernel 1: Sb = bf16((F @ em.T)/TEMP).  BM=256, BN=64, BK=32, grid 256,
// 512 threads (8 waves, wave w owns rows w*32..w*32+31, all 64 cols).
//
// v3 root-cause fix: round 1/2 indexed Brg[]/af[] with a RUNTIME k -> the
// compiler allocated them (and spilled acc state) to scratch (VGPR_Count=40,
// MfmaUtil 7.9%, all pipes idle at 2900 cyc/K-step).  The K-loop is now
// FULLY UNROLLED so every register-array index is a literal (rule #20).
// On top of that:
//   - depth-4 cooperative B prefetch (1 float4/thread/step -> Brg[4]=16 VGPR)
//     gives ~3 K-steps of HBM latency cover for the streamed E rows;
//   - raw s_barrier with lgkmcnt(0)-only wait (no __syncthreads) so global
//     loads stay in flight across the per-step barrier (T4: no vmcnt drain);
//     asm memory clobbers pin the ds_write before / ds_read after the barrier.
// ---------------------------------------------------------------------------
__global__ __launch_bounds__(512, 2)
void gemm_score(const bf16_t* __restrict__ Fb, const float* __restrict__ E,
                bf16_t* __restrict__ Sb) {
    const int tid  = threadIdx.x;
    const int bn   = blockIdx.x;          // 64-col n-stripe
    const int lane = tid & 63;
    const int w    = tid >> 6;            // wave 0..7, owns rows w*32..w*32+31
    const int frow = lane & 15;
    const int quad = (lane >> 4) & 3;

    // Shared double-buffered B tile in MFMA-B fragment-major layout:
    // frag n (512 bf16 = 1 KB) at n*512, lane-slot l' = fr+16*quad at l'*8.
    __shared__ bf16_t Bls[2][2048];       // 8 KB

    f32x4 acc[2][4] = {};                 // [m][n]

    // ---- B cooperative staging: 64 rows x 32 fp32 per K-step.
    // 512 threads x one float4 covers the slab exactly once.
    const int r  = tid >> 3;              // 0..63  (proxy row within stripe)
    const int c4 = (tid & 7) * 4;         // fp32 col within 32
    const float* bsrc = E + (size_t)(bn * 64 + r) * D_DIM + c4;
    const int bdst = (r >> 4) * 512 + ((r & 15) + 16 * (c4 >> 3)) * 8
                   + ((c4 >> 2) & 1) * 4;

    // A frag (m, kt) at Fb[((w*2+m)*64 + kt)*512 + lane*8]
    const bf16_t* Ab0 = Fb + (size_t)((w * 2 + 0) * 64) * 512 + lane * 8;
    const bf16_t* Ab1 = Fb + (size_t)((w * 2 + 1) * 64) * 512 + lane * 8;

    float4 Brg[4];                        // B prefetch, 4 deep (literal idx only)
    bf16x8 af[2][2];                      // A frags, 1 step ahead (literal idx)

    // ---- prologue: issue B batches 0..3, A(0); stage batch 0 into buf 0 ----
#pragma unroll
    for (int p = 0; p < 4; ++p)
        Brg[p] = *(const float4*)(bsrc + p * 32);
    af[0][0] = *(const bf16x8*)(Ab0);
    af[0][1] = *(const bf16x8*)(Ab1);
    {
        bf16x4 h = { (bf16_t)Brg[0].x, (bf16_t)Brg[0].y,
                     (bf16_t)Brg[0].z, (bf16_t)Brg[0].w };
        *(bf16x4*)(&Bls[0][0] + bdst) = h;
    }
    asm volatile("s_waitcnt lgkmcnt(0)" ::: "memory");
    __builtin_amdgcn_s_barrier();
    asm volatile("" ::: "memory");

    // ---- main loop: FULLY UNROLLED so cur/nxt/slot indices are literals ----
#pragma unroll 64
    for (int k = 0; k < 64; ++k) {
        const int cur = k & 1;            // literal after unroll
        const int nxt = cur ^ 1;

        // issue B batch k+4 into the slot freed by batch k (consumed step k-1)
        if (k + 4 < 64)
            Brg[k & 3] = *(const float4*)(bsrc + (k + 4) * 32);
        // issue A frags for step k+1 (Fb is L2-resident)
        if (k + 1 < 64) {
            af[nxt][0] = *(const bf16x8*)(Ab0 + (k + 1) * 512);
            af[nxt][1] = *(const bf16x8*)(Ab1 + (k + 1) * 512);
        }

        // LDS -> regs: 4 B-frags, contiguous 1 KB per wave (conflict-free)
        bf16x8 bg[4];
#pragma unroll
        for (int n = 0; n < 4; ++n)
            bg[n] = *(const bf16x8*)(&Bls[cur][0] + n * 512 + lane * 8);

#pragma unroll
        for (int m = 0; m < 2; ++m)
#pragma unroll
            for (int n = 0; n < 4; ++n)
                acc[m][n] = __builtin_amdgcn_mfma_f32_16x16x32_bf16(
                    af[cur][m], bg[n], acc[m][n], 0, 0, 0);

        // cvt + stage batch k+1 (loaded 3 steps ago -> counted vmcnt, no stall)
        if (k + 1 < 64) {
            bf16x4 h = { (bf16_t)Brg[(k + 1) & 3].x, (bf16_t)Brg[(k + 1) & 3].y,
                         (bf16_t)Brg[(k + 1) & 3].z, (bf16_t)Brg[(k + 1) & 3].w };
            *(bf16x4*)(&Bls[nxt][0] + bdst) = h;
        }

        // ds ops drained (reads AND writes), but vmem stays in flight
        asm volatile("s_waitcnt lgkmcnt(0)" ::: "memory");
        __builtin_amdgcn_s_barrier();
        asm volatile("" ::: "memory");
    }

    // ---- epilogue: C/D layout col=lane&15, row=quad*4+i; fold 1/TEMP ----
#pragma unroll
    for (int m = 0; m < 2; ++m) {
        int gr = w * 32 + m * 16 + quad * 4;
#pragma unroll
        for (int n = 0; n < 4; ++n) {
            int gc = bn * 64 + n * 16 + frow;
#pragma unroll
            for (int i = 0; i < 4; ++i)
                Sb[(size_t)(gr + i) * N_PROXY + gc] =
                    (bf16_t)(acc[m][n][i] * TEMP_INV);
        }
    }
}

// ---------------------------------------------------------------------------
// Kernel 2: per-row top-K + log-softmax loss on bf16 scores.
// 512 threads/row, 32 keys/thread; 16-bit radix select with early exit.
// (unchanged this round — one structural change at a time)
// ---------------------------------------------------------------------------
__device__ __forceinline__ float key16_to_float(uint32_t k) {
    uint32_t bits16 = (k & 0x8000u) ? (k ^ 0x8000u) : ((~k) & 0xFFFFu);
    return __uint_as_float(bits16 << 16);
}

__device__ __forceinline__ int block_sum_i(int v, int tid, volatile int* rbuf) {
#pragma unroll
    for (int o = 32; o > 0; o >>= 1) v += __shfl_down(v, o, 64);
    __syncthreads();
    if ((tid & 63) == 0) rbuf[tid >> 6] = v;
    __syncthreads();
    int s = 0;
#pragma unroll
    for (int w = 0; w < 8; ++w) s += rbuf[w];
    return s;
}

__device__ __forceinline__ float block_sum_f(float v, int tid, volatile float* rbuf) {
#pragma unroll
    for (int o = 32; o > 0; o >>= 1) v += __shfl_down(v, o, 64);
    __syncthreads();
    if ((tid & 63) == 0) rbuf[tid >> 6] = v;
    __syncthreads();
    float s = 0.0f;
#pragma unroll
    for (int w = 0; w < 8; ++w) s += rbuf[w];
    return s;
}

__device__ __forceinline__ uint32_t block_max_u(uint32_t v, int tid,
                                                volatile uint32_t* rbuf) {
#pragma unroll
    for (int o = 32; o > 0; o >>= 1) {
        uint32_t w = __shfl_down(v, o, 64);
        v = (w > v) ? w : v;
    }
    __syncthreads();
    if ((tid & 63) == 0) rbuf[tid >> 6] = v;
    __syncthreads();
    uint32_t r = 0;
#pragma unroll
    for (int w = 0; w < 8; ++w) r = rbuf[w] > r ? rbuf[w] : r;
    return r;
}

__global__ __launch_bounds__(512)
void topk_loss(const bf16_t* __restrict__ S, const int* __restrict__ targets,
               const int* __restrict__ plabel, const int* __restrict__ ptable,
               float* __restrict__ out) {
    const int b    = blockIdx.x;
    const int tid  = threadIdx.x;
    const int lane = tid & 63;
    const int wave = tid >> 6;

    __shared__ int      sh_pos[4];
    __shared__ float    sh_pv[4];
    __shared__ int      sh_d;
    __shared__ int      rbuf_i[8];
    __shared__ float    rbuf_f[8];
    __shared__ uint32_t rbuf_u[8];
    __shared__ uint32_t cand_ls[64];
    __shared__ int      candcnt;
    __shared__ float    sh_numbg;

    const bf16_t* row = S + (size_t)b * N_PROXY;

    if (tid == 0) {
        int t  = targets[b];
        int py = plabel[t];
        int pos[4]; int d = 0;
        for (int j = 0; j < 4; ++j) {
            int p = ptable[py * 4 + j];
            bool dup = false;
            for (int i = 0; i < d; ++i) dup = dup || (pos[i] == p);
            if (!dup) pos[d++] = p;
        }
        sh_d = d;
        for (int j = 0; j < 4; ++j) sh_pos[j] = (j < d) ? pos[j] : -1;
        for (int j = 0; j < 4; ++j) sh_pv[j]  = (j < d) ? (float)row[pos[j]] : 0.0f;
        candcnt = 0;
    }
    __syncthreads();

    const int d  = sh_d;
    const int p0 = sh_pos[0], p1 = sh_pos[1], p2 = sh_pos[2], p3 = sh_pos[3];
    float pv[4];
#pragma unroll
    for (int j = 0; j < 4; ++j) pv[j] = sh_pv[j];

    // ---- 32 bf16 logits/thread as 16-bit sortable keys; positives -> 0 ----
    uint32_t keys[32];
#pragma unroll
    for (int j = 0; j < 4; ++j) {
        int g8 = j * 512 + tid;                     // 8-element granule
        ushort v[8];
        *(uint4*)v = *(const uint4*)(row + (size_t)g8 * 8);
#pragma unroll
        for (int q = 0; q < 8; ++q) {
            int idx = g8 * 8 + q;
            bool isp = (idx == p0) | (idx == p1) | (idx == p2) | (idx == p3);
            uint32_t bits = v[q];
            uint32_t key  = (bits & 0x8000u) ? ((~bits) & 0xFFFFu)
                                             : (bits | 0x8000u);
            keys[j * 8 + q] = isp ? 0u : key;
        }
    }

    const int need = K_SEL - d;              // backgrounds in the top-54 set

    // ---- 16-bit radix select with early exit ----
    uint32_t T = 0;
    for (int bit = 15; bit >= 0; --bit) {
        uint32_t cnd = T | (1u << bit);
        int c = 0;
#pragma unroll
        for (int j = 0; j < 32; ++j) c += (keys[j] >= cnd) ? 1 : 0;
        int ct = block_sum_i(c, tid, rbuf_i);
        if (ct >= need) {
            T = cnd;
            if (ct == need) break;           // selected set is exactly top-need
        }
    }
    const float vT = key16_to_float(T);

    // ---- stability max over backgrounds + positives ----
    uint32_t kmax = 0;
#pragma unroll
    for (int j = 0; j < 32; ++j) kmax = keys[j] > kmax ? keys[j] : kmax;
    kmax = block_max_u(kmax, tid, rbuf_u);
    float mx = key16_to_float(kmax);
    for (int j = 0; j < 4; ++j) if (j < d && pv[j] > mx) mx = pv[j];

    // ---- lse over selected set: strict-greater + exact tie fill + pos ----
    int c1 = 0; float se = 0.0f;
#pragma unroll
    for (int j = 0; j < 32; ++j) {
        if (keys[j] > T) { c1 += 1; se += __expf(key16_to_float(keys[j]) - mx); }
    }
    int   c1t = block_sum_i(c1, tid, rbuf_i);
    float set = block_sum_f(se, tid, rbuf_f);
    set += (float)(need - c1t) * __expf(vT - mx);
    for (int j = 0; j < 4; ++j) if (j < d) set += __expf(pv[j] - mx);
    const float lse = mx + logf(set);

    // ---- numerator: distinct positives + top (P-d) background values ----
    float num = 0.0f;
    for (int j = 0; j < 4; ++j) if (j < d) num += pv[j];
    if (d < P_POS) {
#pragma unroll
        for (int j = 0; j < 32; ++j) {
            if (keys[j] > T) {
                int p = atomicAdd(&candcnt, 1);
                cand_ls[p] = keys[j];
            }
        }
        __syncthreads();
        if (wave == 0) {
            const int cc = candcnt;
            uint32_t v = (lane < cc) ? cand_ls[lane] : T;   // pad with T (exact)
            float s = 0.0f;
            const int need2 = P_POS - d;                    // 1..3
            for (int it = 0; it < need2; ++it) {
                uint32_t m = v;
#pragma unroll
                for (int o = 32; o > 0; o >>= 1) {
                    uint32_t w = __shfl_xor(m, o, 64);
                    m = (w > m) ? w : m;
                }
                s += key16_to_float(m);
                unsigned long long msk = __ballot(v == m);
                int first = __ffsll(msk) - 1;
                if (lane == first) v = 0u;
            }
            if (lane == 0) sh_numbg = s;
        }
        __syncthreads();
        num += sh_numbg;
    }

    const float loss_b = lse - num * (1.0f / P_POS);
    if (tid == 0) atomicAdd(out, loss_b * (1.0f / B_SZ));
}

// ---------------------------------------------------------------------------
extern "C" void kernel_launch(void* const* d_in, const int* in_sizes, int n_in,
                              void* d_out, int out_size, void* d_ws, size_t ws_size,
                              hipStream_t stream) {
    const float* F       = (const float*)d_in[0];   // features [256,2048]
    const float* E       = (const float*)d_in[1];   // global_memory [16384,2048]
    const int*   targets = (const int*)d_in[2];     // [256]
    const int*   plabel  = (const int*)d_in[3];     // [32768]
    const int*   ptable  = (const int*)d_in[4];     // [4096,4]

    bf16_t* Fb = (bf16_t*)d_ws;                                     // 1 MB, frag-major
    bf16_t* Sb = (bf16_t*)((char*)d_ws + (size_t)B_SZ * D_DIM * 2); // 8 MB
    float*  out = (float*)d_out;

    // out is zeroed by conv_feat (stream-ordered before topk_loss's atomics)
    hipLaunchKernelGGL(conv_feat, dim3(256), dim3(256), 0, stream, F, Fb, out);
    hipLaunchKernelGGL(gemm_score, dim3(N_PROXY / 64), dim3(512), 0, stream,
                       Fb, E, Sb);
    hipLaunchKernelGGL(topk_loss, dim3(B_SZ), dim3(512), 0, stream,
                       Sb, targets, plabel, ptable, out);
}